// Round 1
// baseline (649.312 us; speedup 1.0000x reference)
//
#include <hip/hip_runtime.h>

#define NN 50000
#define NE 800000
#define INF 128
#define HF 64

// ---------------- degree / normalization ----------------

__global__ void deg_kernel(const int* __restrict__ dst, float* __restrict__ deg) {
    int e = blockIdx.x * blockDim.x + threadIdx.x;
    if (e < NE) atomicAdd(&deg[dst[e]], 1.0f);
}

__global__ void dinv_kernel(const float* __restrict__ deg, float* __restrict__ dinv) {
    int i = blockIdx.x * blockDim.x + threadIdx.x;
    if (i < NN) {
        float d = deg[i];
        d = d < 1.0f ? 1.0f : d;
        dinv[i] = 1.0f / sqrtf(d);
    }
}

// ---------------- GEMM1: X = relu(F @ W1^T + b1), 128 -> 64 ----------------
// block = 512 threads = 8 waves; each wave computes one row n (lane j = output feat).
// W1 (64x128) staged transposed in LDS with +1 pad to avoid write conflicts.

__global__ __launch_bounds__(512) void gemm1_kernel(const float* __restrict__ F,
                                                    const float* __restrict__ W1,
                                                    const float* __restrict__ b1,
                                                    float* __restrict__ X) {
    __shared__ float w[INF][HF + 1];  // w[k][j] = W1[j][k]
    int tid = threadIdx.x;
    for (int idx = tid; idx < HF * INF; idx += 512) {
        int j = idx >> 7;        // W1 row
        int k = idx & 127;       // W1 col
        w[k][j] = W1[idx];
    }
    __syncthreads();

    int j  = tid & 63;
    int nl = tid >> 6;           // 0..7
    int n  = blockIdx.x * 8 + nl;
    if (n >= NN) return;

    const float* frow = F + (size_t)n * INF;
    float acc = 0.0f;
#pragma unroll 8
    for (int k = 0; k < INF; ++k) acc += frow[k] * w[k][j];
    acc += b1[j];
    X[(size_t)n * HF + j] = acc > 0.0f ? acc : 0.0f;
}

// ---------------- scatter: agg[dst] += f[src] * dinv[src] ----------------
// block = 256 threads -> 4 edges/block; wave shares one edge (uniform src/dst loads).

__global__ __launch_bounds__(256) void scatter_kernel(const int* __restrict__ src,
                                                      const int* __restrict__ dst,
                                                      const float* __restrict__ f,
                                                      const float* __restrict__ dinv,
                                                      float* __restrict__ agg) {
    int e = blockIdx.x * 4 + (threadIdx.x >> 6);
    int j = threadIdx.x & 63;
    if (e >= NE) return;
    int s = src[e];
    int d = dst[e];
    float v = f[(size_t)s * HF + j] * dinv[s];
    atomicAdd(&agg[(size_t)d * HF + j], v);
}

// ---------------- Laplacian finish: out = f - agg * dinv[n] ----------------

__global__ __launch_bounds__(256) void lap_finish(const float* __restrict__ f,
                                                  const float* __restrict__ agg,
                                                  const float* __restrict__ dinv,
                                                  float* __restrict__ out) {
    int gid = blockIdx.x * blockDim.x + threadIdx.x;
    if (gid < NN * HF) {
        int n = gid >> 6;
        out[gid] = f[gid] - agg[gid] * dinv[n];
    }
}

// ---------------- build combined M matrices (absorb thetas into W2) ----------------
// THETAS (d=2): [3,-3,0.75], [0,3,-1.5], [0,0,0.75]
// out = f0@M0^T + f1@M1^T + f2@M2^T + b2, where (A|B|C) = W2 column blocks:
//   M0 = 3A ; M1 = -3A + 3B ; M2 = 0.75A - 1.5B + 0.75C
// Mc stored row-major (64 x 192): [M0 | M1 | M2]

__global__ void build_m(const float* __restrict__ W2, float* __restrict__ Mc) {
    int gid = blockIdx.x * blockDim.x + threadIdx.x;
    if (gid >= HF * 3 * HF) return;
    int j = gid / 192;
    int k = gid % 192;
    const float* row = W2 + (size_t)j * 192;
    float v;
    if (k < 64) {
        v = 3.0f * row[k];
    } else if (k < 128) {
        int c = k - 64;
        v = -3.0f * row[c] + 3.0f * row[64 + c];
    } else {
        int c = k - 128;
        v = 0.75f * row[c] - 1.5f * row[64 + c] + 0.75f * row[128 + c];
    }
    Mc[gid] = v;
}

// ---------------- GEMM2: out = f0@M0^T + f1@M1^T + f2@M2^T + b2 ----------------

__global__ __launch_bounds__(512) void gemm2_kernel(const float* __restrict__ f0,
                                                    const float* __restrict__ f1,
                                                    const float* __restrict__ f2,
                                                    const float* __restrict__ Mc,
                                                    const float* __restrict__ b2,
                                                    float* __restrict__ out) {
    __shared__ float m[192][HF + 1];  // m[k][j] = Mc[j][k]
    int tid = threadIdx.x;
    for (int idx = tid; idx < HF * 192; idx += 512) {
        int j = idx / 192;
        int k = idx % 192;
        m[k][j] = Mc[idx];
    }
    __syncthreads();

    int j  = tid & 63;
    int nl = tid >> 6;
    int n  = blockIdx.x * 8 + nl;
    if (n >= NN) return;

    const float* r0 = f0 + (size_t)n * HF;
    const float* r1 = f1 + (size_t)n * HF;
    const float* r2 = f2 + (size_t)n * HF;
    float acc = b2[j];
#pragma unroll 8
    for (int k = 0; k < HF; ++k) acc += r0[k] * m[k][j];
#pragma unroll 8
    for (int k = 0; k < HF; ++k) acc += r1[k] * m[64 + k][j];
#pragma unroll 8
    for (int k = 0; k < HF; ++k) acc += r2[k] * m[128 + k][j];
    out[(size_t)n * HF + j] = acc;
}

// ---------------- launch ----------------

extern "C" void kernel_launch(void* const* d_in, const int* in_sizes, int n_in,
                              void* d_out, int out_size, void* d_ws, size_t ws_size,
                              hipStream_t stream) {
    const float* features = (const float*)d_in[0];
    const int*   src      = (const int*)d_in[1];
    const int*   dst      = (const int*)d_in[2];
    const float* W1       = (const float*)d_in[3];
    const float* b1       = (const float*)d_in[4];
    const float* W2       = (const float*)d_in[5];
    const float* b2       = (const float*)d_in[6];
    float* out = (float*)d_out;

    // workspace layout (floats)
    float* ws   = (float*)d_ws;
    float* f0   = ws;                    // 3.2M
    float* f1   = f0 + (size_t)NN * HF;  // 3.2M
    float* f2   = f1 + (size_t)NN * HF;  // 3.2M
    float* agg  = f2 + (size_t)NN * HF;  // 3.2M
    float* deg  = agg + (size_t)NN * HF; // 50K
    float* dinv = deg + NN;              // 50K
    float* Mc   = dinv + NN;             // 12288

    // zero deg + agg (workspace is poisoned 0xAA before every launch)
    hipMemsetAsync(deg, 0, NN * sizeof(float), stream);
    hipMemsetAsync(agg, 0, (size_t)NN * HF * sizeof(float), stream);

    deg_kernel<<<(NE + 255) / 256, 256, 0, stream>>>(dst, deg);
    dinv_kernel<<<(NN + 255) / 256, 256, 0, stream>>>(deg, dinv);

    gemm1_kernel<<<(NN + 7) / 8, 512, 0, stream>>>(features, W1, b1, f0);

    // f1 = L f0
    scatter_kernel<<<(NE + 3) / 4, 256, 0, stream>>>(src, dst, f0, dinv, agg);
    lap_finish<<<(NN * HF + 255) / 256, 256, 0, stream>>>(f0, agg, dinv, f1);

    // f2 = L f1
    hipMemsetAsync(agg, 0, (size_t)NN * HF * sizeof(float), stream);
    scatter_kernel<<<(NE + 3) / 4, 256, 0, stream>>>(src, dst, f1, dinv, agg);
    lap_finish<<<(NN * HF + 255) / 256, 256, 0, stream>>>(f1, agg, dinv, f2);

    // combined output GEMM
    build_m<<<(HF * 192 + 255) / 256, 256, 0, stream>>>(W2, Mc);
    gemm2_kernel<<<(NN + 7) / 8, 512, 0, stream>>>(f0, f1, f2, Mc, b2, out);
}

// Round 2
// 512.199 us; speedup vs baseline: 1.2677x; 1.2677x over previous
//
#include <hip/hip_runtime.h>

#define NN 50000
#define NE 800000
#define INF 128
#define HF 64

// ---------------- CSR build: count, scan, fill ----------------

__global__ void count_kernel(const int* __restrict__ dst, int* __restrict__ degi) {
    int e = blockIdx.x * blockDim.x + threadIdx.x;
    if (e < NE) atomicAdd(&degi[dst[e]], 1);
}

// single block of 1024 threads: exclusive prefix sum over degi -> rowstart/cursor, plus dinv
__global__ __launch_bounds__(1024) void scan_kernel(const int* __restrict__ degi,
                                                    int* __restrict__ rowstart,
                                                    int* __restrict__ cursor,
                                                    float* __restrict__ dinv) {
    __shared__ int sums[1024];
    int tid = threadIdx.x;
    const int C = (NN + 1023) / 1024;  // 49
    int start = tid * C;
    int end   = start + C; if (end > NN) end = NN;
    int local = 0;
    for (int i = start; i < end; ++i) local += degi[i];
    sums[tid] = local;
    __syncthreads();
    for (int off = 1; off < 1024; off <<= 1) {
        int v = (tid >= off) ? sums[tid - off] : 0;
        __syncthreads();
        sums[tid] += v;
        __syncthreads();
    }
    int run = sums[tid] - local;  // exclusive prefix
    for (int i = start; i < end; ++i) {
        rowstart[i] = run;
        cursor[i]   = run;
        int d = degi[i];
        dinv[i] = rsqrtf((float)(d < 1 ? 1 : d));
        run += d;
    }
    if (tid == 1023) rowstart[NN] = NE;
}

__global__ void fill_kernel(const int* __restrict__ src, const int* __restrict__ dst,
                            int* __restrict__ cursor, int* __restrict__ csr_src) {
    int e = blockIdx.x * blockDim.x + threadIdx.x;
    if (e < NE) {
        int d = dst[e];
        int pos = atomicAdd(&cursor[d], 1);
        csr_src[pos] = src[e];
    }
}

// ---------------- GEMM1: X = relu(F @ W1^T + b1), 128 -> 64 ----------------

__global__ __launch_bounds__(512) void gemm1_kernel(const float* __restrict__ F,
                                                    const float* __restrict__ W1,
                                                    const float* __restrict__ b1,
                                                    float* __restrict__ X) {
    __shared__ float w[INF][HF + 1];  // w[k][j] = W1[j][k]
    int tid = threadIdx.x;
    for (int idx = tid; idx < HF * INF; idx += 512) {
        int j = idx >> 7;
        int k = idx & 127;
        w[k][j] = W1[idx];
    }
    __syncthreads();

    int j  = tid & 63;
    int nl = tid >> 6;
    int n  = blockIdx.x * 8 + nl;
    if (n >= NN) return;

    const float* frow = F + (size_t)n * INF;
    float acc = 0.0f;
#pragma unroll 8
    for (int k = 0; k < INF; ++k) acc += frow[k] * w[k][j];
    acc += b1[j];
    X[(size_t)n * HF + j] = acc > 0.0f ? acc : 0.0f;
}

// ---------------- fused gather + Laplacian: out = f - (sum_in f[s]*dinv[s]) * dinv[n] ----
// one wave per destination node; lane j = feature j. Edge srcs broadcast via shfl.

__global__ __launch_bounds__(256) void gather_lap(const int* __restrict__ rowstart,
                                                  const int* __restrict__ csr_src,
                                                  const float* __restrict__ dinv,
                                                  const float* __restrict__ f,
                                                  float* __restrict__ out) {
    int n = blockIdx.x * 4 + (threadIdx.x >> 6);
    int j = threadIdx.x & 63;
    if (n >= NN) return;
    int row = rowstart[n];
    int end = rowstart[n + 1];

    float acc0 = 0.f, acc1 = 0.f, acc2 = 0.f, acc3 = 0.f;
    for (int base = row; base < end; base += 64) {
        int idx = base + j;
        int sv = 0; float dv = 0.f;
        if (idx < end) { sv = csr_src[idx]; dv = dinv[sv]; }
        int cnt = end - base; if (cnt > 64) cnt = 64;
        int k = 0;
        for (; k + 3 < cnt; k += 4) {
            int   s0 = __shfl(sv, k),     s1 = __shfl(sv, k + 1);
            int   s2 = __shfl(sv, k + 2), s3 = __shfl(sv, k + 3);
            float w0 = __shfl(dv, k),     w1 = __shfl(dv, k + 1);
            float w2 = __shfl(dv, k + 2), w3 = __shfl(dv, k + 3);
            acc0 += f[(size_t)s0 * HF + j] * w0;
            acc1 += f[(size_t)s1 * HF + j] * w1;
            acc2 += f[(size_t)s2 * HF + j] * w2;
            acc3 += f[(size_t)s3 * HF + j] * w3;
        }
        for (; k < cnt; ++k) {
            int   s = __shfl(sv, k);
            float w = __shfl(dv, k);
            acc0 += f[(size_t)s * HF + j] * w;
        }
    }
    float acc = (acc0 + acc1) + (acc2 + acc3);
    size_t o = (size_t)n * HF + j;
    out[o] = f[o] - acc * dinv[n];
}

// ---------------- build combined M matrices (absorb thetas into W2) ----------------
// THETAS (d=2): [3,-3,0.75], [0,3,-1.5], [0,0,0.75]
//   M0 = 3A ; M1 = -3A + 3B ; M2 = 0.75A - 1.5B + 0.75C  (A|B|C = W2 col blocks)

__global__ void build_m(const float* __restrict__ W2, float* __restrict__ Mc) {
    int gid = blockIdx.x * blockDim.x + threadIdx.x;
    if (gid >= HF * 3 * HF) return;
    int j = gid / 192;
    int k = gid % 192;
    const float* row = W2 + (size_t)j * 192;
    float v;
    if (k < 64) {
        v = 3.0f * row[k];
    } else if (k < 128) {
        int c = k - 64;
        v = -3.0f * row[c] + 3.0f * row[64 + c];
    } else {
        int c = k - 128;
        v = 0.75f * row[c] - 1.5f * row[64 + c] + 0.75f * row[128 + c];
    }
    Mc[gid] = v;
}

// ---------------- GEMM2: out = f0@M0^T + f1@M1^T + f2@M2^T + b2 ----------------

__global__ __launch_bounds__(512) void gemm2_kernel(const float* __restrict__ f0,
                                                    const float* __restrict__ f1,
                                                    const float* __restrict__ f2,
                                                    const float* __restrict__ Mc,
                                                    const float* __restrict__ b2,
                                                    float* __restrict__ out) {
    __shared__ float m[192][HF + 1];  // m[k][j] = Mc[j][k]
    int tid = threadIdx.x;
    for (int idx = tid; idx < HF * 192; idx += 512) {
        int j = idx / 192;
        int k = idx % 192;
        m[k][j] = Mc[idx];
    }
    __syncthreads();

    int j  = tid & 63;
    int nl = tid >> 6;
    int n  = blockIdx.x * 8 + nl;
    if (n >= NN) return;

    const float* r0 = f0 + (size_t)n * HF;
    const float* r1 = f1 + (size_t)n * HF;
    const float* r2 = f2 + (size_t)n * HF;
    float acc = b2[j];
#pragma unroll 8
    for (int k = 0; k < HF; ++k) acc += r0[k] * m[k][j];
#pragma unroll 8
    for (int k = 0; k < HF; ++k) acc += r1[k] * m[64 + k][j];
#pragma unroll 8
    for (int k = 0; k < HF; ++k) acc += r2[k] * m[128 + k][j];
    out[(size_t)n * HF + j] = acc;
}

// ---------------- launch ----------------

extern "C" void kernel_launch(void* const* d_in, const int* in_sizes, int n_in,
                              void* d_out, int out_size, void* d_ws, size_t ws_size,
                              hipStream_t stream) {
    const float* features = (const float*)d_in[0];
    const int*   src      = (const int*)d_in[1];
    const int*   dst      = (const int*)d_in[2];
    const float* W1       = (const float*)d_in[3];
    const float* b1       = (const float*)d_in[4];
    const float* W2       = (const float*)d_in[5];
    const float* b2       = (const float*)d_in[6];
    float* out = (float*)d_out;

    // workspace layout
    float* ws    = (float*)d_ws;
    float* f0    = ws;                      // NN*HF
    float* f1    = f0 + (size_t)NN * HF;
    float* f2    = f1 + (size_t)NN * HF;
    float* dinv  = f2 + (size_t)NN * HF;    // NN
    float* Mc    = dinv + NN;               // 64*192
    int*   degi     = (int*)(Mc + HF * 192);   // NN
    int*   rowstart = degi + NN;               // NN+1
    int*   cursor   = rowstart + NN + 1;       // NN
    int*   csr_src  = cursor + NN;             // NE

    hipMemsetAsync(degi, 0, NN * sizeof(int), stream);

    // CSR build
    count_kernel<<<(NE + 255) / 256, 256, 0, stream>>>(dst, degi);
    scan_kernel<<<1, 1024, 0, stream>>>(degi, rowstart, cursor, dinv);
    fill_kernel<<<(NE + 255) / 256, 256, 0, stream>>>(src, dst, cursor, csr_src);

    // GEMM1
    gemm1_kernel<<<(NN + 7) / 8, 512, 0, stream>>>(features, W1, b1, f0);

    // f1 = L f0 ; f2 = L f1  (fused gather + finish, no atomics)
    gather_lap<<<(NN + 3) / 4, 256, 0, stream>>>(rowstart, csr_src, dinv, f0, f1);
    gather_lap<<<(NN + 3) / 4, 256, 0, stream>>>(rowstart, csr_src, dinv, f1, f2);

    // combined output GEMM
    build_m<<<(HF * 192 + 255) / 256, 256, 0, stream>>>(W2, Mc);
    gemm2_kernel<<<(NN + 7) / 8, 512, 0, stream>>>(f0, f1, f2, Mc, b2, out);
}

// Round 3
// 372.623 us; speedup vs baseline: 1.7425x; 1.3746x over previous
//
#include <hip/hip_runtime.h>

#define NN 50000
#define NE 800000
#define INF 128
#define HF 64
#define SCAN_CHUNK 256
#define NBLK ((NN + SCAN_CHUNK - 1) / SCAN_CHUNK)  // 196

// ---------------- CSR build: count, hierarchical scan, fill ----------------

__global__ void count_kernel(const int* __restrict__ dst, int* __restrict__ degi) {
    int e = blockIdx.x * blockDim.x + threadIdx.x;
    if (e < NE) atomicAdd(&degi[dst[e]], 1);
}

// phase 1: per-block partial sums (coalesced)
__global__ __launch_bounds__(256) void partial_kernel(const int* __restrict__ degi,
                                                      int* __restrict__ partials) {
    __shared__ int red[256];
    int tid = threadIdx.x;
    int i = blockIdx.x * 256 + tid;
    int v = (i < NN) ? degi[i] : 0;
    red[tid] = v;
    __syncthreads();
    for (int off = 128; off > 0; off >>= 1) {
        if (tid < off) red[tid] += red[tid + off];
        __syncthreads();
    }
    if (tid == 0) partials[blockIdx.x] = red[0];
}

// phase 2: one wave scans the 196 partials -> exclusive block offsets
__global__ __launch_bounds__(64) void scan_partials(const int* __restrict__ partials,
                                                    int* __restrict__ offsets) {
    int tid = threadIdx.x;  // 0..63
    int vals[4];
    int sum = 0;
#pragma unroll
    for (int k = 0; k < 4; ++k) {
        int idx = tid * 4 + k;
        int v = (idx < NBLK) ? partials[idx] : 0;
        vals[k] = sum;       // prefix within this thread's chunk
        sum += v;
    }
    int orig = sum;
#pragma unroll
    for (int off = 1; off < 64; off <<= 1) {
        int t = __shfl_up(sum, off);
        if (tid >= off) sum += t;
    }
    int excl = sum - orig;   // exclusive prefix across threads
#pragma unroll
    for (int k = 0; k < 4; ++k) {
        int idx = tid * 4 + k;
        if (idx < NBLK) offsets[idx] = excl + vals[k];
    }
}

// phase 3: per-block local scan + offset -> rowstart/cursor/dinv (coalesced)
__global__ __launch_bounds__(256) void scan_finish(const int* __restrict__ degi,
                                                   const int* __restrict__ offsets,
                                                   int* __restrict__ rowstart,
                                                   int* __restrict__ cursor,
                                                   float* __restrict__ dinv) {
    __shared__ int s[256];
    int tid = threadIdx.x;
    int i = blockIdx.x * 256 + tid;
    int v = (i < NN) ? degi[i] : 0;
    s[tid] = v;
    __syncthreads();
    for (int off = 1; off < 256; off <<= 1) {
        int t = (tid >= off) ? s[tid - off] : 0;
        __syncthreads();
        s[tid] += t;
        __syncthreads();
    }
    if (i < NN) {
        int excl = s[tid] - v + offsets[blockIdx.x];
        rowstart[i] = excl;
        cursor[i]   = excl;
        dinv[i] = rsqrtf((float)(v < 1 ? 1 : v));
        if (i == NN - 1) rowstart[NN] = NE;
    }
}

__global__ void fill_kernel(const int* __restrict__ src, const int* __restrict__ dst,
                            int* __restrict__ cursor, int* __restrict__ csr_src) {
    int e = blockIdx.x * blockDim.x + threadIdx.x;
    if (e < NE) {
        int d = dst[e];
        int pos = atomicAdd(&cursor[d], 1);
        csr_src[pos] = src[e];
    }
}

// ---------------- GEMM1: X = relu(F @ W1^T + b1), 128 -> 64 ----------------

__global__ __launch_bounds__(512) void gemm1_kernel(const float* __restrict__ F,
                                                    const float* __restrict__ W1,
                                                    const float* __restrict__ b1,
                                                    float* __restrict__ X) {
    __shared__ float w[INF][HF + 1];  // w[k][j] = W1[j][k]
    int tid = threadIdx.x;
    for (int idx = tid; idx < HF * INF; idx += 512) {
        int j = idx >> 7;
        int k = idx & 127;
        w[k][j] = W1[idx];
    }
    __syncthreads();

    int j  = tid & 63;
    int nl = tid >> 6;
    int n  = blockIdx.x * 8 + nl;
    if (n >= NN) return;

    const float* frow = F + (size_t)n * INF;
    float acc = 0.0f;
#pragma unroll 8
    for (int k = 0; k < INF; ++k) acc += frow[k] * w[k][j];
    acc += b1[j];
    X[(size_t)n * HF + j] = acc > 0.0f ? acc : 0.0f;
}

// ---------------- fused gather + Laplacian: out = f - (sum_in f[s]*dinv[s]) * dinv[n] ----

__global__ __launch_bounds__(256) void gather_lap(const int* __restrict__ rowstart,
                                                  const int* __restrict__ csr_src,
                                                  const float* __restrict__ dinv,
                                                  const float* __restrict__ f,
                                                  float* __restrict__ out) {
    int n = blockIdx.x * 4 + (threadIdx.x >> 6);
    int j = threadIdx.x & 63;
    if (n >= NN) return;
    int row = rowstart[n];
    int end = rowstart[n + 1];

    float acc0 = 0.f, acc1 = 0.f, acc2 = 0.f, acc3 = 0.f;
    for (int base = row; base < end; base += 64) {
        int idx = base + j;
        int sv = 0; float dv = 0.f;
        if (idx < end) { sv = csr_src[idx]; dv = dinv[sv]; }
        int cnt = end - base; if (cnt > 64) cnt = 64;
        int k = 0;
        for (; k + 3 < cnt; k += 4) {
            int   s0 = __shfl(sv, k),     s1 = __shfl(sv, k + 1);
            int   s2 = __shfl(sv, k + 2), s3 = __shfl(sv, k + 3);
            float w0 = __shfl(dv, k),     w1 = __shfl(dv, k + 1);
            float w2 = __shfl(dv, k + 2), w3 = __shfl(dv, k + 3);
            acc0 += f[(size_t)s0 * HF + j] * w0;
            acc1 += f[(size_t)s1 * HF + j] * w1;
            acc2 += f[(size_t)s2 * HF + j] * w2;
            acc3 += f[(size_t)s3 * HF + j] * w3;
        }
        for (; k < cnt; ++k) {
            int   s = __shfl(sv, k);
            float w = __shfl(dv, k);
            acc0 += f[(size_t)s * HF + j] * w;
        }
    }
    float acc = (acc0 + acc1) + (acc2 + acc3);
    size_t o = (size_t)n * HF + j;
    out[o] = f[o] - acc * dinv[n];
}

// ---------------- build combined M matrices (absorb thetas into W2) ----------------
// THETAS (d=2): [3,-3,0.75], [0,3,-1.5], [0,0,0.75]
//   M0 = 3A ; M1 = -3A + 3B ; M2 = 0.75A - 1.5B + 0.75C  (A|B|C = W2 col blocks)

__global__ void build_m(const float* __restrict__ W2, float* __restrict__ Mc) {
    int gid = blockIdx.x * blockDim.x + threadIdx.x;
    if (gid >= HF * 3 * HF) return;
    int j = gid / 192;
    int k = gid % 192;
    const float* row = W2 + (size_t)j * 192;
    float v;
    if (k < 64) {
        v = 3.0f * row[k];
    } else if (k < 128) {
        int c = k - 64;
        v = -3.0f * row[c] + 3.0f * row[64 + c];
    } else {
        int c = k - 128;
        v = 0.75f * row[c] - 1.5f * row[64 + c] + 0.75f * row[128 + c];
    }
    Mc[gid] = v;
}

// ---------------- GEMM2: out = f0@M0^T + f1@M1^T + f2@M2^T + b2 ----------------

__global__ __launch_bounds__(512) void gemm2_kernel(const float* __restrict__ f0,
                                                    const float* __restrict__ f1,
                                                    const float* __restrict__ f2,
                                                    const float* __restrict__ Mc,
                                                    const float* __restrict__ b2,
                                                    float* __restrict__ out) {
    __shared__ float m[192][HF + 1];  // m[k][j] = Mc[j][k]
    int tid = threadIdx.x;
    for (int idx = tid; idx < HF * 192; idx += 512) {
        int j = idx / 192;
        int k = idx % 192;
        m[k][j] = Mc[idx];
    }
    __syncthreads();

    int j  = tid & 63;
    int nl = tid >> 6;
    int n  = blockIdx.x * 8 + nl;
    if (n >= NN) return;

    const float* r0 = f0 + (size_t)n * HF;
    const float* r1 = f1 + (size_t)n * HF;
    const float* r2 = f2 + (size_t)n * HF;
    float acc = b2[j];
#pragma unroll 8
    for (int k = 0; k < HF; ++k) acc += r0[k] * m[k][j];
#pragma unroll 8
    for (int k = 0; k < HF; ++k) acc += r1[k] * m[64 + k][j];
#pragma unroll 8
    for (int k = 0; k < HF; ++k) acc += r2[k] * m[128 + k][j];
    out[(size_t)n * HF + j] = acc;
}

// ---------------- launch ----------------

extern "C" void kernel_launch(void* const* d_in, const int* in_sizes, int n_in,
                              void* d_out, int out_size, void* d_ws, size_t ws_size,
                              hipStream_t stream) {
    const float* features = (const float*)d_in[0];
    const int*   src      = (const int*)d_in[1];
    const int*   dst      = (const int*)d_in[2];
    const float* W1       = (const float*)d_in[3];
    const float* b1       = (const float*)d_in[4];
    const float* W2       = (const float*)d_in[5];
    const float* b2       = (const float*)d_in[6];
    float* out = (float*)d_out;

    // workspace layout
    float* ws    = (float*)d_ws;
    float* f0    = ws;                      // NN*HF
    float* f1    = f0 + (size_t)NN * HF;
    float* f2    = f1 + (size_t)NN * HF;
    float* dinv  = f2 + (size_t)NN * HF;    // NN
    float* Mc    = dinv + NN;               // 64*192
    int*   degi     = (int*)(Mc + HF * 192);   // NN
    int*   rowstart = degi + NN;               // NN+1
    int*   cursor   = rowstart + NN + 1;       // NN
    int*   csr_src  = cursor + NN;             // NE
    int*   partials = csr_src + NE;            // NBLK
    int*   offsets  = partials + NBLK;         // NBLK

    hipMemsetAsync(degi, 0, NN * sizeof(int), stream);

    // CSR build
    count_kernel<<<(NE + 255) / 256, 256, 0, stream>>>(dst, degi);
    partial_kernel<<<NBLK, 256, 0, stream>>>(degi, partials);
    scan_partials<<<1, 64, 0, stream>>>(partials, offsets);
    scan_finish<<<NBLK, 256, 0, stream>>>(degi, offsets, rowstart, cursor, dinv);
    fill_kernel<<<(NE + 255) / 256, 256, 0, stream>>>(src, dst, cursor, csr_src);

    // GEMM1
    gemm1_kernel<<<(NN + 7) / 8, 512, 0, stream>>>(features, W1, b1, f0);

    // f1 = L f0 ; f2 = L f1  (fused gather + finish, no atomics)
    gather_lap<<<(NN + 3) / 4, 256, 0, stream>>>(rowstart, csr_src, dinv, f0, f1);
    gather_lap<<<(NN + 3) / 4, 256, 0, stream>>>(rowstart, csr_src, dinv, f1, f2);

    // combined output GEMM
    build_m<<<(HF * 192 + 255) / 256, 256, 0, stream>>>(W2, Mc);
    gemm2_kernel<<<(NN + 7) / 8, 512, 0, stream>>>(f0, f1, f2, Mc, b2, out);
}